// Round 5
// baseline (360.402 us; speedup 1.0000x reference)
//
#include <hip/hip_runtime.h>
#include <hip/hip_bf16.h>
#include <stdint.h>

// ---------------------------------------------------------------------------
// MatryoshkaAttention: B=2, T=4096, D=1024, active_dim=512 -> H=8, hd=64.
// fp32 in/out (sniffed on-device), bf16 MFMA compute.
// R16: flash deep pipeline. R15's LDS-shared staging worked (413->357us) but
// ended each step with s_waitcnt vmcnt(0) (drain) -- staging latency only
// covered by one step's compute. Now: 3 LDS buffers, 2 tiles in flight,
// counted s_waitcnt vmcnt(4) at step end (tile k+1 complete, k+2 flying with
// a full extra step of cover). T4 rule: never drain vmcnt to 0 in-loop.
// Everything except flash_kernel identical to R15.
// NO launch_bounds min arg anywhere (R6/R8: forcing VGPR caps below footprint
// -> scratch spill).
// ---------------------------------------------------------------------------

typedef __bf16 bf16;
typedef bf16  bf16x8 __attribute__((ext_vector_type(8)));
typedef bf16  bf16x4v __attribute__((ext_vector_type(4)));
typedef float f32x4  __attribute__((ext_vector_type(4)));
typedef uint32_t u32x4 __attribute__((ext_vector_type(4)));

#define SCL 0.18033688011112042f   /* 0.125 * log2(e): p = 2^(s*SCL) = e^(s/8) */
#define NEG_BIG (-30000.0f)

static __device__ __forceinline__ f32x4 mfma_bf16(bf16x8 a, bf16x8 b, f32x4 c) {
    return __builtin_amdgcn_mfma_f32_16x16x32_bf16(a, b, c, 0, 0, 0);
}

// async global->LDS, 16B per lane; LDS dest = uniform base + lane*16.
static __device__ __forceinline__ void gl_lds(const bf16* g, bf16* l) {
    __builtin_amdgcn_global_load_lds(
        (const __attribute__((address_space(1))) uint32_t*)(g),
        (__attribute__((address_space(3))) uint32_t*)(l), 16, 0, 0);
}

// ---------------------------------------------------------------------------
__global__ __launch_bounds__(256) void sniff_dtype(
    const uint16_t* __restrict__ x, int* __restrict__ flag)
{
    __shared__ int cnt;
    if (threadIdx.x == 0) cnt = 0;
    __syncthreads();
    int local = 0;
    for (int i = threadIdx.x; i < 2048; i += 256) {
        const int e = (x[i] >> 7) & 0xFF;
        if (e >= 0xC0) ++local;
    }
    if (local) atomicAdd(&cnt, local);
    __syncthreads();
    if (threadIdx.x == 0) *flag = (cnt >= 8) ? 1 : 0;
}

// ---------------------------------------------------------------------------
// One launch converts all five tensors (cols 0..511 of [rows][1024]) into
// packed bf16. Blocks 0..2047: x -> xb. Blocks 2048..2559: weights -> wb.
// ---------------------------------------------------------------------------
__global__ __launch_bounds__(256) void convert_all(
    const void* __restrict__ x,
    const void* __restrict__ wq, const void* __restrict__ wk,
    const void* __restrict__ wv, const void* __restrict__ wo,
    bf16* __restrict__ xb, bf16* __restrict__ wb,
    const int* __restrict__ flag)
{
    const int bid = blockIdx.x;
    const void* src;
    bf16* dst;
    int sub;
    if (bid < 2048) { src = x; dst = xb; sub = bid; }
    else {
        const int w = bid - 2048;
        const int wsel = w >> 7;
        src = (wsel == 0) ? wq : (wsel == 1) ? wk : (wsel == 2) ? wv : wo;
        dst = wb + (size_t)wsel * 262144;
        sub = w & 127;
    }
    const int i = (sub * 256 + threadIdx.x) * 8;
    const int r = i >> 9, c = i & 511;
    bf16x8 v;
    if (*flag) {
        const float* s = (const float*)src + (size_t)r * 1024 + c;
        f32x4 f0 = *(const f32x4*)s;
        f32x4 f1 = *(const f32x4*)(s + 4);
#pragma unroll
        for (int j = 0; j < 4; ++j) { v[j] = (bf16)f0[j]; v[4 + j] = (bf16)f1[j]; }
    } else {
        v = *(const bf16x8*)((const bf16*)src + (size_t)r * 1024 + c);
    }
    *(bf16x8*)(dst + (size_t)r * 512 + c) = v;
}

// ---------------------------------------------------------------------------
// Fused QKV NT GEMM with register ping-pong prefetch.
// A:[8192][512]; B:[1536][512] = wq|wk|wv contiguous.
// sel 0=Q head layout (pre-scaled by SCL), 1=K head layout,
// sel 2=V transposed (LDS transpose).
// ---------------------------------------------------------------------------
struct GF { bf16x8 a; bf16x8 b[4]; };

__global__ __launch_bounds__(256) void gemm_qkv(
    const bf16* __restrict__ A, const bf16* __restrict__ B,
    bf16* __restrict__ Qb, bf16* __restrict__ Kb, bf16* __restrict__ Vb)
{
    const int n0   = blockIdx.x * 64;
    const int m0   = blockIdx.y * 64;
    const int wave = threadIdx.x >> 6;
    const int lane = threadIdx.x & 63;
    const int col  = lane & 15;
    const int quad = lane >> 4;

    const bf16* __restrict__ Ar = A + (size_t)(m0 + wave * 16 + col) * 512 + quad * 8;
    const bf16* __restrict__ Br = B + (size_t)(n0 + col) * 512 + quad * 8;

    f32x4 acc[4];
#pragma unroll
    for (int nt = 0; nt < 4; ++nt)
#pragma unroll
        for (int r = 0; r < 4; ++r) acc[nt][r] = 0.0f;

    auto load_f = [&](int k0, GF& f) {
        f.a = *(const bf16x8*)(Ar + k0);
#pragma unroll
        for (int nt = 0; nt < 4; ++nt)
            f.b[nt] = *(const bf16x8*)(Br + (size_t)(nt * 16) * 512 + k0);
    };
    auto do_mfma = [&](const GF& f) {
#pragma unroll
        for (int nt = 0; nt < 4; ++nt)
            acc[nt] = mfma_bf16(f.a, f.b[nt], acc[nt]);
    };

    GF f0, f1;
    load_f(0, f0);
#pragma unroll
    for (int k0 = 0; k0 < 512; k0 += 64) {
        if (k0 + 32 < 512) load_f(k0 + 32, f1);
        do_mfma(f0);
        if (k0 + 64 < 512) load_f(k0 + 64, f0);
        do_mfma(f1);
    }

    const int sel = n0 >> 9;
    const int bb  = m0 >> 12;

    if (sel < 2) {
        bf16* __restrict__ dst = (sel == 0) ? Qb : Kb;
        const float qs = (sel == 0) ? SCL : 1.0f;   // fold softmax scale into Q
#pragma unroll
        for (int nt = 0; nt < 4; ++nt) {
#pragma unroll
            for (int r = 0; r < 4; ++r) {
                const int row = m0 + wave * 16 + quad * 4 + r;
                const int cn  = (n0 & 511) + nt * 16 + col;
                const int t = row & 4095;
                const int h = cn >> 6, d = cn & 63;
                dst[((size_t)(bb * 8 + h) * 4096 + t) * 64 + d] = (bf16)(acc[nt][r] * qs);
            }
        }
    } else {
        __shared__ __align__(16) bf16 T[64][72];
#pragma unroll
        for (int nt = 0; nt < 4; ++nt)
#pragma unroll
            for (int r = 0; r < 4; ++r)
                T[wave * 16 + quad * 4 + r][nt * 16 + col] = (bf16)acc[nt][r];
        __syncthreads();

        const int h0 = (n0 - 1024) >> 6;
        const int d  = threadIdx.x >> 2;
        const int tp = (threadIdx.x & 3) * 16;
        bf16 vals[16];
#pragma unroll
        for (int i = 0; i < 16; ++i) vals[i] = T[tp + i][d];
        bf16* dst = Vb + ((size_t)(bb * 8 + h0) * 64 + d) * 4096 + (m0 & 4095) + tp;
        *(bf16x8*)dst       = *(bf16x8*)&vals[0];
        *(bf16x8*)(dst + 8) = *(bf16x8*)&vals[8];
    }
}

// ---------------------------------------------------------------------------
// Out-projection NT GEMM + fused pad, with ping-pong prefetch.
// grid (16,128). n0<512: C = A*wo^T; n0>=512: zero-fill tile.
// ---------------------------------------------------------------------------
__global__ __launch_bounds__(256) void gemm_out_pad(
    const bf16* __restrict__ A, const bf16* __restrict__ B, void* __restrict__ C,
    const int* __restrict__ flag)
{
    const int n0   = blockIdx.x * 64;
    const int m0   = blockIdx.y * 64;
    const int isf  = *flag;

    if (n0 >= 512) {
        const int row = m0 + (threadIdx.x >> 2);
        const int c0  = n0 + (threadIdx.x & 3) * 16;
        if (isf) {
            float* p = (float*)C + (size_t)row * 1024 + c0;
            f32x4 z; z[0] = 0.f; z[1] = 0.f; z[2] = 0.f; z[3] = 0.f;
#pragma unroll
            for (int j = 0; j < 4; ++j) *(f32x4*)(p + j * 4) = z;
        } else {
            bf16* p = (bf16*)C + (size_t)row * 1024 + c0;
            u32x4 z; z[0] = 0u; z[1] = 0u; z[2] = 0u; z[3] = 0u;
            *(u32x4*)p = z; *(u32x4*)(p + 8) = z;
        }
        return;
    }

    const int wave = threadIdx.x >> 6;
    const int lane = threadIdx.x & 63;
    const int col  = lane & 15;
    const int quad = lane >> 4;

    const bf16* __restrict__ Ar = A + (size_t)(m0 + wave * 16 + col) * 512 + quad * 8;
    const bf16* __restrict__ Br = B + (size_t)(n0 + col) * 512 + quad * 8;

    f32x4 acc[4];
#pragma unroll
    for (int nt = 0; nt < 4; ++nt)
#pragma unroll
        for (int r = 0; r < 4; ++r) acc[nt][r] = 0.0f;

    auto load_f = [&](int k0, GF& f) {
        f.a = *(const bf16x8*)(Ar + k0);
#pragma unroll
        for (int nt = 0; nt < 4; ++nt)
            f.b[nt] = *(const bf16x8*)(Br + (size_t)(nt * 16) * 512 + k0);
    };
    auto do_mfma = [&](const GF& f) {
#pragma unroll
        for (int nt = 0; nt < 4; ++nt)
            acc[nt] = mfma_bf16(f.a, f.b[nt], acc[nt]);
    };

    GF f0, f1;
    load_f(0, f0);
#pragma unroll
    for (int k0 = 0; k0 < 512; k0 += 64) {
        if (k0 + 32 < 512) load_f(k0 + 32, f1);
        do_mfma(f0);
        if (k0 + 64 < 512) load_f(k0 + 64, f0);
        do_mfma(f1);
    }

#pragma unroll
    for (int nt = 0; nt < 4; ++nt) {
#pragma unroll
        for (int r = 0; r < 4; ++r) {
            const int row = m0 + wave * 16 + quad * 4 + r;
            const int cn  = n0 + nt * 16 + col;
            const float f = acc[nt][r];
            if (isf) ((float*)C)[(size_t)row * 1024 + cn] = f;
            else     ((bf16*)C)[(size_t)row * 1024 + cn] = (bf16)f;
        }
    }
}

// ---------------------------------------------------------------------------
// Flash causal attention, LDS-shared K/V tiles, 3-buffer deep pipeline.
// Block = (bh, qb0, s): q-block qb0 with K-tiles [s? qb0+1 : 0, s? 2qb0+2 :
// qb0+1), then q-block 31-qb0 with K-tiles [s? 0 : 32-qb0, s? 32-qb0 :
// 64-2qb0). Every block = 33 tile-steps. Waves own 32 q-rows each (2 strips,
// S^T operand swap). K/V tiles in 3 LDS buffers, 2 tiles in flight, counted
// s_waitcnt vmcnt(4) at step end (4 gl_lds per wave per tile; in-order
// retirement means tile k+1's loads are among the 8 oldest -> complete).
// Chunk-XOR swizzle (src pre-swizzled, linear LDS dest).
// ---------------------------------------------------------------------------
__global__ __launch_bounds__(256) void flash_kernel(
    const bf16* __restrict__ Q, const bf16* __restrict__ K,
    const bf16* __restrict__ Vt,
    float* __restrict__ Opart, float* __restrict__ Spart)
{
    const int wave = threadIdx.x >> 6;
    const int lane = threadIdx.x & 63;
    const int qc   = lane & 15;
    const int quad = lane >> 4;

    const int bh  = blockIdx.x & 15;
    const int qb0 = (blockIdx.x >> 4) & 15;
    const int s   = blockIdx.x >> 8;          // 0..1

    const bf16* __restrict__ Qh = Q  + (size_t)bh * (4096 * 64);
    const bf16* __restrict__ Kh = K  + (size_t)bh * (4096 * 64);
    const bf16* __restrict__ Vh = Vt + (size_t)bh * (64 * 4096);

    __shared__ __align__(16) bf16 Ksh[3][64][64];
    __shared__ __align__(16) bf16 Vsh[3][64][64];
    __shared__ __align__(16) bf16 Plds[4][2][16][72];  // per-wave, no barriers
    bf16* myPA = &Plds[wave][0][0][0];
    bf16* myPB = &Plds[wave][1][0][0];

    // stage tile kb into buf: each wave stages K rows [16w,16w+16) and V
    // d-rows [16w,16w+16): 2+2 gl_lds (1KB each). LDS linear; global src
    // pre-swizzled: LDS[r][chunk] = G[r][chunk ^ (r&7)] (chunk = 8 elems).
    auto stage = [&](int kb, int buf) {
        const int rr = lane >> 3, cc = lane & 7;    // rr 0..7, cc 0..7
#pragma unroll
        for (int j = 0; j < 2; ++j) {
            const int r0 = wave * 16 + j * 8;
            const int r  = r0 + rr;
            const int cs = (cc ^ rr) * 8;           // r&7 == rr (r0 % 8 == 0)
            gl_lds(Kh + (size_t)(kb * 64 + r) * 64 + cs, &Ksh[buf][r0][0]);
            gl_lds(Vh + (size_t)r * 4096 + kb * 64 + cs, &Vsh[buf][r0][0]);
        }
    };

    for (int chunk = 0; chunk < 2; ++chunk) {
        const int qb = chunk ? (31 - qb0) : qb0;
        int k0, k1;
        if (chunk == 0) { k0 = s ? (qb0 + 1) : 0;   k1 = s ? (2 * qb0 + 2) : (qb0 + 1); }
        else            { k0 = s ? 0 : (32 - qb0);  k1 = s ? (32 - qb0) : (64 - 2 * qb0); }

        const int qrow   = qb * 128 + wave * 32;    // this wave's 32-row band
        const int ktmaxw = 2 * qb + (wave >> 1);    // wave's diagonal tile

        bf16x8 aqA0 = *(const bf16x8*)(Qh + (size_t)(qrow + qc) * 64 + quad * 8);
        bf16x8 aqA1 = *(const bf16x8*)(Qh + (size_t)(qrow + qc) * 64 + 32 + quad * 8);
        bf16x8 aqB0 = *(const bf16x8*)(Qh + (size_t)(qrow + 16 + qc) * 64 + quad * 8);
        bf16x8 aqB1 = *(const bf16x8*)(Qh + (size_t)(qrow + 16 + qc) * 64 + 32 + quad * 8);

        f32x4 oA[4], oB[4];
        f32x4 s4A, s4B;
#pragma unroll
        for (int r = 0; r < 4; ++r) { s4A[r] = 0.f; s4B[r] = 0.f; }
#pragma unroll
        for (int nt = 0; nt < 4; ++nt)
#pragma unroll
            for (int r = 0; r < 4; ++r) { oA[nt][r] = 0.f; oB[nt][r] = 0.f; }

        // ---- pipeline prologue: 2 tiles in flight, wait for the first ----
        int b0 = 0, b1 = 1, b2 = 2;
        stage(k0, b0);
        if (k0 + 1 < k1) {
            stage(k0 + 1, b1);
            asm volatile("s_waitcnt vmcnt(4)" ::: "memory");
        } else {
            asm volatile("s_waitcnt vmcnt(0)" ::: "memory");
        }
        __syncthreads();

        for (int kb = k0; kb < k1; ++kb) {
            const bool more2 = (kb + 2 < k1);
            if (more2) stage(kb + 2, b2);
            const int buf = b0;

            if (kb <= ktmaxw) {
                const int kbase = kb * 64;
                const bool diag = (kb == ktmaxw);
                const int h = qc & 7;

                // ---- QK^T + exp + pack to P-LDS ----
#pragma unroll
                for (int nt = 0; nt < 4; ++nt) {
                    const int r = nt * 16 + qc;
                    bf16x8 kf0 = *(const bf16x8*)&Ksh[buf][r][(quad ^ h) * 8];
                    bf16x8 kf1 = *(const bf16x8*)&Ksh[buf][r][((quad + 4) ^ h) * 8];

                    f32x4 sA; sA[0] = 0.f; sA[1] = 0.f; sA[2] = 0.f; sA[3] = 0.f;
                    sA = mfma_bf16(kf0, aqA0, sA);
                    sA = mfma_bf16(kf1, aqA1, sA);
                    f32x4 sB; sB[0] = 0.f; sB[1] = 0.f; sB[2] = 0.f; sB[3] = 0.f;
                    sB = mfma_bf16(kf0, aqB0, sB);
                    sB = mfma_bf16(kf1, aqB1, sB);

                    bf16x4v pkA, pkB;
#pragma unroll
                    for (int r2 = 0; r2 < 4; ++r2) {
                        float vA = sA[r2];          // Q pre-scaled: no mul here
                        float vB = sB[r2];
                        if (diag) {
                            const int kg = kbase + nt * 16 + quad * 4 + r2;
                            if (kg > qrow + qc)      vA = NEG_BIG;
                            if (kg > qrow + 16 + qc) vB = NEG_BIG;
                        }
                        const float pA = __builtin_amdgcn_exp2f(vA);
                        const float pB = __builtin_amdgcn_exp2f(vB);
                        s4A[r2] += pA;
                        s4B[r2] += pB;
                        pkA[r2] = (bf16)pA;
                        pkB[r2] = (bf16)pB;
                    }
                    *(bf16x4v*)(myPA + qc * 72 + nt * 16 + quad * 4) = pkA;
                    *(bf16x4v*)(myPB + qc * 72 + nt * 16 + quad * 4) = pkB;
                }

                // ---- PV for both strips, V from LDS ----
#pragma unroll
                for (int ks = 0; ks < 2; ++ks) {
                    bf16x8 apA = *(const bf16x8*)(myPA + qc * 72 + ks * 32 + quad * 8);
                    bf16x8 apB = *(const bf16x8*)(myPB + qc * 72 + ks * 32 + quad * 8);
#pragma unroll
                    for (int nt = 0; nt < 4; ++nt) {
                        const int d = nt * 16 + qc;
                        bf16x8 vf = *(const bf16x8*)&Vsh[buf][d][((4 * ks + quad) ^ h) * 8];
                        oA[nt] = mfma_bf16(apA, vf, oA[nt]);
                        oB[nt] = mfma_bf16(apB, vf, oB[nt]);
                    }
                }
            }

            // ---- counted wait: tile kb+1 complete, kb+2 stays in flight ----
            if (more2) asm volatile("s_waitcnt vmcnt(4)" ::: "memory");
            else       asm volatile("s_waitcnt vmcnt(0)" ::: "memory");
            __syncthreads();
            const int tswap = b0; b0 = b1; b1 = b2; b2 = tswap;
        }

        // ---- epilogue: write partial (qb, s) ----
        float sumA = (s4A[0] + s4A[1]) + (s4A[2] + s4A[3]);
        float sumB = (s4B[0] + s4B[1]) + (s4B[2] + s4B[3]);
        sumA += __shfl_xor(sumA, 16, 64);
        sumA += __shfl_xor(sumA, 32, 64);
        sumB += __shfl_xor(sumB, 16, 64);
        sumB += __shfl_xor(sumB, 32, 64);

        const int pw = (qb * 16 + bh) * 2 + s;
        float* op = Opart + (size_t)pw * 8192 + (size_t)(wave * 32) * 64;
#pragma unroll
        for (int nt = 0; nt < 4; ++nt)
#pragma unroll
            for (int r = 0; r < 4; ++r) {
                op[(quad * 4 + r) * 64 + nt * 16 + qc]        = oA[nt][r];
                op[1024 + (quad * 4 + r) * 64 + nt * 16 + qc] = oB[nt][r];
            }
        if (quad == 0) {
            float* sp = Spart + (size_t)pw * 128 + wave * 32;
            sp[qc]      = sumA;
            sp[16 + qc] = sumB;
        }
    }
}

// ---------------------------------------------------------------------------
// Combine: 512 units (qb*16+bh) x 128 rows; sum 2 partials, normalize.
// Grid 512 x 256 thr: col = tid&63, row group = tid>>6 (32 rows each).
// ---------------------------------------------------------------------------
__global__ __launch_bounds__(256) void combine_kernel(
    const float* __restrict__ Opart, const float* __restrict__ Spart,
    bf16* __restrict__ Ob)
{
    const int u  = blockIdx.x;            // 0..511
    const int qb = u >> 4;
    const int bh = u & 15;
    const int c  = threadIdx.x & 63;
    const int g  = threadIdx.x >> 6;
    const int b = bh >> 3, h = bh & 7;

    const float* o0 = Opart + (size_t)(u * 2) * 8192;
    const float* o1 = o0 + 8192;
    const float* s0 = Spart + (size_t)(u * 2) * 128;
    const float* s1 = s0 + 128;

#pragma unroll 4
    for (int rr = 0; rr < 32; ++rr) {
        const int row = g * 32 + rr;
        const float inv = 1.0f / (s0[row] + s1[row]);
        const float v = (o0[row * 64 + c] + o1[row * 64 + c]) * inv;
        const int t = qb * 128 + row;
        Ob[((size_t)b * 4096 + t) * 512 + h * 64 + c] = (bf16)v;
    }
}

extern "C" void kernel_launch(void* const* d_in, const int* in_sizes, int n_in,
                              void* d_out, int out_size, void* d_ws, size_t ws_size,
                              hipStream_t stream)
{
    (void)in_sizes; (void)n_in; (void)out_size; (void)ws_size;
    const void* x  = d_in[0];
    const void* wq = d_in[1];
    const void* wk = d_in[2];
    const void* wv = d_in[3];
    const void* wo = d_in[4];

    char* wsb = (char*)d_ws;
    bf16* xb   = (bf16*)(wsb + 0);          // [8192][512] (aliased by Ob)
    bf16* Ob   = (bf16*)(wsb + 0);
    bf16* wb   = (bf16*)(wsb + 8388608);    // [2048][512]: wq|wk|wv|wo
    bf16* wob  = wb + 3 * 262144;
    bf16* Qb   = (bf16*)(wsb + 10485760);   // [2][8][4096][64]
    bf16* Kb   = (bf16*)(wsb + 18874368);
    bf16* Vb   = (bf16*)(wsb + 27262976);   // [2][8][64][4096]
    int*  flag = (int*) (wsb + 35651584);
    float* Opart = (float*)(wsb + 35651600);   // [1024 pw][128][64] fp32 = 33.5MB
    float* Spart = (float*)(wsb + 69206032);   // [1024 pw][128] fp32 = 512KB

    const dim3 blk(256);

    sniff_dtype<<<1, blk, 0, stream>>>((const uint16_t*)x, flag);
    convert_all<<<2560, blk, 0, stream>>>(x, wq, wk, wv, wo, xb, wb, flag);

    gemm_qkv<<<dim3(24, 128), blk, 0, stream>>>(xb, wb, Qb, Kb, Vb);

    flash_kernel<<<dim3(512), blk, 0, stream>>>(Qb, Kb, Vb, Opart, Spart);
    combine_kernel<<<dim3(512), blk, 0, stream>>>(Opart, Spart, Ob);

    gemm_out_pad<<<dim3(16, 128), blk, 0, stream>>>(Ob, wob, d_out, flag);
}

// Round 6
// 277.610 us; speedup vs baseline: 1.2982x; 1.2982x over previous
//
#include <hip/hip_runtime.h>
#include <hip/hip_bf16.h>
#include <stdint.h>

// ---------------------------------------------------------------------------
// MatryoshkaAttention: B=2, T=4096, D=1024, active_dim=512 -> H=8, hd=64.
// fp32 in/out (sniffed on-device), bf16 MFMA compute.
// R17: gemm_qkv rebuilt on the m97 GEMM structure. R16 counters: MfmaUtil
// 4.3%, VALUBusy 2.5%, occ 55% -> vmem-latency-bound 64-tile GEMM with
// per-wave direct global loads (no sharing). Now: 128x128 tile, BK=64,
// double-buffered LDS staged via global_load_lds (16B), XOR-swizzled
// (pre-swizzled global src, linear LDS dest -- same proven flash pattern),
// 4 waves 2x2, acc[4][4], vmcnt(0)+barrier per K-step (m97 ladder, 874 TF
// class). V epilogue: direct bf16x4 stores (r-index contiguous in t).
// Flash kept from R16. NO launch_bounds min arg anywhere (R6/R8).
// ---------------------------------------------------------------------------

typedef __bf16 bf16;
typedef bf16  bf16x8 __attribute__((ext_vector_type(8)));
typedef bf16  bf16x4v __attribute__((ext_vector_type(4)));
typedef float f32x4  __attribute__((ext_vector_type(4)));
typedef uint32_t u32x4 __attribute__((ext_vector_type(4)));

#define SCL 0.18033688011112042f   /* 0.125 * log2(e): p = 2^(s*SCL) = e^(s/8) */
#define NEG_BIG (-30000.0f)

static __device__ __forceinline__ f32x4 mfma_bf16(bf16x8 a, bf16x8 b, f32x4 c) {
    return __builtin_amdgcn_mfma_f32_16x16x32_bf16(a, b, c, 0, 0, 0);
}

// async global->LDS, 16B per lane; LDS dest = wave-uniform base + lane*16.
static __device__ __forceinline__ void gl_lds(const bf16* g, bf16* l) {
    __builtin_amdgcn_global_load_lds(
        (const __attribute__((address_space(1))) uint32_t*)(g),
        (__attribute__((address_space(3))) uint32_t*)(l), 16, 0, 0);
}

// ---------------------------------------------------------------------------
__global__ __launch_bounds__(256) void sniff_dtype(
    const uint16_t* __restrict__ x, int* __restrict__ flag)
{
    __shared__ int cnt;
    if (threadIdx.x == 0) cnt = 0;
    __syncthreads();
    int local = 0;
    for (int i = threadIdx.x; i < 2048; i += 256) {
        const int e = (x[i] >> 7) & 0xFF;
        if (e >= 0xC0) ++local;
    }
    if (local) atomicAdd(&cnt, local);
    __syncthreads();
    if (threadIdx.x == 0) *flag = (cnt >= 8) ? 1 : 0;
}

// ---------------------------------------------------------------------------
// One launch converts all five tensors (cols 0..511 of [rows][1024]) into
// packed bf16. Blocks 0..2047: x -> xb. Blocks 2048..2559: weights -> wb.
// ---------------------------------------------------------------------------
__global__ __launch_bounds__(256) void convert_all(
    const void* __restrict__ x,
    const void* __restrict__ wq, const void* __restrict__ wk,
    const void* __restrict__ wv, const void* __restrict__ wo,
    bf16* __restrict__ xb, bf16* __restrict__ wb,
    const int* __restrict__ flag)
{
    const int bid = blockIdx.x;
    const void* src;
    bf16* dst;
    int sub;
    if (bid < 2048) { src = x; dst = xb; sub = bid; }
    else {
        const int w = bid - 2048;
        const int wsel = w >> 7;
        src = (wsel == 0) ? wq : (wsel == 1) ? wk : (wsel == 2) ? wv : wo;
        dst = wb + (size_t)wsel * 262144;
        sub = w & 127;
    }
    const int i = (sub * 256 + threadIdx.x) * 8;
    const int r = i >> 9, c = i & 511;
    bf16x8 v;
    if (*flag) {
        const float* s = (const float*)src + (size_t)r * 1024 + c;
        f32x4 f0 = *(const f32x4*)s;
        f32x4 f1 = *(const f32x4*)(s + 4);
#pragma unroll
        for (int j = 0; j < 4; ++j) { v[j] = (bf16)f0[j]; v[4 + j] = (bf16)f1[j]; }
    } else {
        v = *(const bf16x8*)((const bf16*)src + (size_t)r * 1024 + c);
    }
    *(bf16x8*)(dst + (size_t)r * 512 + c) = v;
}

// ---------------------------------------------------------------------------
// Fused QKV NT GEMM, m97 structure: 128x128 tile, BK=64, LDS double-buffer
// staged via global_load_lds with chunk-XOR swizzle. Grid (12, 64).
// A:[8192][512]; B:[1536][512] = wq|wk|wv contiguous.
// bx 0-3: Q (pre-scaled by SCL), 4-7: K, 8-11: V (transposed direct store).
// ---------------------------------------------------------------------------
__global__ __launch_bounds__(256) void gemm_qkv(
    const bf16* __restrict__ A, const bf16* __restrict__ B,
    bf16* __restrict__ Qb, bf16* __restrict__ Kb, bf16* __restrict__ Vb)
{
    const int bx   = blockIdx.x;            // n-tile 0..11
    const int n0   = bx * 128;
    const int m0   = blockIdx.y * 128;
    const int wave = threadIdx.x >> 6;
    const int lane = threadIdx.x & 63;
    const int col  = lane & 15;
    const int quad = lane >> 4;
    const int wr   = wave >> 1, wc = wave & 1;

    __shared__ __align__(16) bf16 As[2][128][64];
    __shared__ __align__(16) bf16 Bs[2][128][64];

    const int rr = lane >> 3, cc = lane & 7;
    const int cs = (cc ^ rr) * 8;           // pre-swizzled source chunk

    // stage K-step kt into buf: per wave 32 rows of A and 32 rows of B,
    // 4 gl_lds issues each (8 rows x 64 cols = 1KB per issue). LDS linear;
    // global src column pre-swizzled: LDS[r][ch] = G[r][ch ^ (r&7)].
    auto stage = [&](int kt, int buf) {
#pragma unroll
        for (int j = 0; j < 4; ++j) {
            const int r0 = wave * 32 + j * 8;      // r0 % 8 == 0 -> row&7 == rr
            gl_lds(A + (size_t)(m0 + r0 + rr) * 512 + kt * 64 + cs, &As[buf][r0][0]);
            gl_lds(B + (size_t)(n0 + r0 + rr) * 512 + kt * 64 + cs, &Bs[buf][r0][0]);
        }
    };

    f32x4 acc[4][4];
#pragma unroll
    for (int m = 0; m < 4; ++m)
#pragma unroll
        for (int n = 0; n < 4; ++n)
#pragma unroll
            for (int r = 0; r < 4; ++r) acc[m][n][r] = 0.0f;

    stage(0, 0);
    asm volatile("s_waitcnt vmcnt(0)" ::: "memory");
    __syncthreads();

    for (int kt = 0; kt < 8; ++kt) {
        const int buf = kt & 1;
        if (kt + 1 < 8) stage(kt + 1, buf ^ 1);

#pragma unroll
        for (int kk = 0; kk < 2; ++kk) {
            bf16x8 af[4], bfr[4];
#pragma unroll
            for (int m = 0; m < 4; ++m) {
                const int row = wr * 64 + m * 16 + col;
                af[m] = *(const bf16x8*)&As[buf][row][(((kk << 2) + quad) ^ (col & 7)) * 8];
            }
#pragma unroll
            for (int n = 0; n < 4; ++n) {
                const int row = wc * 64 + n * 16 + col;
                bfr[n] = *(const bf16x8*)&Bs[buf][row][(((kk << 2) + quad) ^ (col & 7)) * 8];
            }
#pragma unroll
            for (int m = 0; m < 4; ++m)
#pragma unroll
                for (int n = 0; n < 4; ++n)
                    acc[m][n] = mfma_bf16(af[m], bfr[n], acc[m][n]);
        }

        asm volatile("s_waitcnt vmcnt(0)" ::: "memory");
        __syncthreads();
    }

    const int bb = m0 >> 12;

    if (bx < 8) {
        bf16* __restrict__ dst = (bx < 4) ? Qb : Kb;
        const float qs = (bx < 4) ? SCL : 1.0f;     // fold softmax scale into Q
#pragma unroll
        for (int m = 0; m < 4; ++m) {
#pragma unroll
            for (int n = 0; n < 4; ++n) {
#pragma unroll
                for (int r = 0; r < 4; ++r) {
                    const int row = m0 + wr * 64 + m * 16 + quad * 4 + r;
                    const int cnl = (n0 & 511) + wc * 64 + n * 16 + col;
                    const int t = row & 4095;
                    const int h = cnl >> 6, d = cnl & 63;
                    dst[((size_t)(bb * 8 + h) * 4096 + t) * 64 + d] = (bf16)(acc[m][n][r] * qs);
                }
            }
        }
    } else {
        // V: transposed store. acc r-index is contiguous in t -> bf16x4.
        const int h0 = (n0 - 1024) >> 6;            // 0,2,4,6
#pragma unroll
        for (int m = 0; m < 4; ++m) {
#pragma unroll
            for (int n = 0; n < 4; ++n) {
                bf16x4v pk;
#pragma unroll
                for (int r = 0; r < 4; ++r) pk[r] = (bf16)acc[m][n][r];
                const int d  = wc * 64 + n * 16 + col;      // 0..127 in tile
                const int t  = (m0 & 4095) + wr * 64 + m * 16 + quad * 4;
                *(bf16x4v*)(Vb + ((size_t)(bb * 8 + h0 + (d >> 6)) * 64 + (d & 63)) * 4096 + t) = pk;
            }
        }
    }
}

// ---------------------------------------------------------------------------
// Out-projection NT GEMM + fused pad, with ping-pong prefetch.
// grid (16,128). n0<512: C = A*wo^T; n0>=512: zero-fill tile.
// ---------------------------------------------------------------------------
struct GF { bf16x8 a; bf16x8 b[4]; };

__global__ __launch_bounds__(256) void gemm_out_pad(
    const bf16* __restrict__ A, const bf16* __restrict__ B, void* __restrict__ C,
    const int* __restrict__ flag)
{
    const int n0   = blockIdx.x * 64;
    const int m0   = blockIdx.y * 64;
    const int isf  = *flag;

    if (n0 >= 512) {
        const int row = m0 + (threadIdx.x >> 2);
        const int c0  = n0 + (threadIdx.x & 3) * 16;
        if (isf) {
            float* p = (float*)C + (size_t)row * 1024 + c0;
            f32x4 z; z[0] = 0.f; z[1] = 0.f; z[2] = 0.f; z[3] = 0.f;
#pragma unroll
            for (int j = 0; j < 4; ++j) *(f32x4*)(p + j * 4) = z;
        } else {
            bf16* p = (bf16*)C + (size_t)row * 1024 + c0;
            u32x4 z; z[0] = 0u; z[1] = 0u; z[2] = 0u; z[3] = 0u;
            *(u32x4*)p = z; *(u32x4*)(p + 8) = z;
        }
        return;
    }

    const int wave = threadIdx.x >> 6;
    const int lane = threadIdx.x & 63;
    const int col  = lane & 15;
    const int quad = lane >> 4;

    const bf16* __restrict__ Ar = A + (size_t)(m0 + wave * 16 + col) * 512 + quad * 8;
    const bf16* __restrict__ Br = B + (size_t)(n0 + col) * 512 + quad * 8;

    f32x4 acc[4];
#pragma unroll
    for (int nt = 0; nt < 4; ++nt)
#pragma unroll
        for (int r = 0; r < 4; ++r) acc[nt][r] = 0.0f;

    auto load_f = [&](int k0, GF& f) {
        f.a = *(const bf16x8*)(Ar + k0);
#pragma unroll
        for (int nt = 0; nt < 4; ++nt)
            f.b[nt] = *(const bf16x8*)(Br + (size_t)(nt * 16) * 512 + k0);
    };
    auto do_mfma = [&](const GF& f) {
#pragma unroll
        for (int nt = 0; nt < 4; ++nt)
            acc[nt] = mfma_bf16(f.a, f.b[nt], acc[nt]);
    };

    GF f0, f1;
    load_f(0, f0);
#pragma unroll
    for (int k0 = 0; k0 < 512; k0 += 64) {
        if (k0 + 32 < 512) load_f(k0 + 32, f1);
        do_mfma(f0);
        if (k0 + 64 < 512) load_f(k0 + 64, f0);
        do_mfma(f1);
    }

#pragma unroll
    for (int nt = 0; nt < 4; ++nt) {
#pragma unroll
        for (int r = 0; r < 4; ++r) {
            const int row = m0 + wave * 16 + quad * 4 + r;
            const int cn  = n0 + nt * 16 + col;
            const float f = acc[nt][r];
            if (isf) ((float*)C)[(size_t)row * 1024 + cn] = f;
            else     ((bf16*)C)[(size_t)row * 1024 + cn] = (bf16)f;
        }
    }
}

// ---------------------------------------------------------------------------
// Flash causal attention, LDS-shared K/V tiles, 3-buffer deep pipeline (R16).
// ---------------------------------------------------------------------------
__global__ __launch_bounds__(256) void flash_kernel(
    const bf16* __restrict__ Q, const bf16* __restrict__ K,
    const bf16* __restrict__ Vt,
    float* __restrict__ Opart, float* __restrict__ Spart)
{
    const int wave = threadIdx.x >> 6;
    const int lane = threadIdx.x & 63;
    const int qc   = lane & 15;
    const int quad = lane >> 4;

    const int bh  = blockIdx.x & 15;
    const int qb0 = (blockIdx.x >> 4) & 15;
    const int s   = blockIdx.x >> 8;          // 0..1

    const bf16* __restrict__ Qh = Q  + (size_t)bh * (4096 * 64);
    const bf16* __restrict__ Kh = K  + (size_t)bh * (4096 * 64);
    const bf16* __restrict__ Vh = Vt + (size_t)bh * (64 * 4096);

    __shared__ __align__(16) bf16 Ksh[3][64][64];
    __shared__ __align__(16) bf16 Vsh[3][64][64];
    __shared__ __align__(16) bf16 Plds[4][2][16][72];  // per-wave, no barriers
    bf16* myPA = &Plds[wave][0][0][0];
    bf16* myPB = &Plds[wave][1][0][0];

    auto stage = [&](int kb, int buf) {
        const int rr = lane >> 3, cc = lane & 7;    // rr 0..7, cc 0..7
#pragma unroll
        for (int j = 0; j < 2; ++j) {
            const int r0 = wave * 16 + j * 8;
            const int r  = r0 + rr;
            const int cs = (cc ^ rr) * 8;           // r&7 == rr (r0 % 8 == 0)
            gl_lds(Kh + (size_t)(kb * 64 + r) * 64 + cs, &Ksh[buf][r0][0]);
            gl_lds(Vh + (size_t)r * 4096 + kb * 64 + cs, &Vsh[buf][r0][0]);
        }
    };

    for (int chunk = 0; chunk < 2; ++chunk) {
        const int qb = chunk ? (31 - qb0) : qb0;
        int k0, k1;
        if (chunk == 0) { k0 = s ? (qb0 + 1) : 0;   k1 = s ? (2 * qb0 + 2) : (qb0 + 1); }
        else            { k0 = s ? 0 : (32 - qb0);  k1 = s ? (32 - qb0) : (64 - 2 * qb0); }

        const int qrow   = qb * 128 + wave * 32;    // this wave's 32-row band
        const int ktmaxw = 2 * qb + (wave >> 1);    // wave's diagonal tile

        bf16x8 aqA0 = *(const bf16x8*)(Qh + (size_t)(qrow + qc) * 64 + quad * 8);
        bf16x8 aqA1 = *(const bf16x8*)(Qh + (size_t)(qrow + qc) * 64 + 32 + quad * 8);
        bf16x8 aqB0 = *(const bf16x8*)(Qh + (size_t)(qrow + 16 + qc) * 64 + quad * 8);
        bf16x8 aqB1 = *(const bf16x8*)(Qh + (size_t)(qrow + 16 + qc) * 64 + 32 + quad * 8);

        f32x4 oA[4], oB[4];
        f32x4 s4A, s4B;
#pragma unroll
        for (int r = 0; r < 4; ++r) { s4A[r] = 0.f; s4B[r] = 0.f; }
#pragma unroll
        for (int nt = 0; nt < 4; ++nt)
#pragma unroll
            for (int r = 0; r < 4; ++r) { oA[nt][r] = 0.f; oB[nt][r] = 0.f; }

        // ---- pipeline prologue: 2 tiles in flight, wait for the first ----
        int b0 = 0, b1 = 1, b2 = 2;
        stage(k0, b0);
        if (k0 + 1 < k1) {
            stage(k0 + 1, b1);
            asm volatile("s_waitcnt vmcnt(4)" ::: "memory");
        } else {
            asm volatile("s_waitcnt vmcnt(0)" ::: "memory");
        }
        __syncthreads();

        for (int kb = k0; kb < k1; ++kb) {
            const bool more2 = (kb + 2 < k1);
            if (more2) stage(kb + 2, b2);
            const int buf = b0;

            if (kb <= ktmaxw) {
                const int kbase = kb * 64;
                const bool diag = (kb == ktmaxw);
                const int h = qc & 7;

                // ---- QK^T + exp + pack to P-LDS ----
#pragma unroll
                for (int nt = 0; nt < 4; ++nt) {
                    const int r = nt * 16 + qc;
                    bf16x8 kf0 = *(const bf16x8*)&Ksh[buf][r][(quad ^ h) * 8];
                    bf16x8 kf1 = *(const bf16x8*)&Ksh[buf][r][((quad + 4) ^ h) * 8];

                    f32x4 sA; sA[0] = 0.f; sA[1] = 0.f; sA[2] = 0.f; sA[3] = 0.f;
                    sA = mfma_bf16(kf0, aqA0, sA);
                    sA = mfma_bf16(kf1, aqA1, sA);
                    f32x4 sB; sB[0] = 0.f; sB[1] = 0.f; sB[2] = 0.f; sB[3] = 0.f;
                    sB = mfma_bf16(kf0, aqB0, sB);
                    sB = mfma_bf16(kf1, aqB1, sB);

                    bf16x4v pkA, pkB;
#pragma unroll
                    for (int r2 = 0; r2 < 4; ++r2) {
                        float vA = sA[r2];          // Q pre-scaled: no mul here
                        float vB = sB[r2];
                        if (diag) {
                            const int kg = kbase + nt * 16 + quad * 4 + r2;
                            if (kg > qrow + qc)      vA = NEG_BIG;
                            if (kg > qrow + 16 + qc) vB = NEG_BIG;
                        }
                        const float pA = __builtin_amdgcn_exp2f(vA);
                        const float pB = __builtin_amdgcn_exp2f(vB);
                        s4A[r2] += pA;
                        s4B[r2] += pB;
                        pkA[r2] = (bf16)pA;
                        pkB[r2] = (bf16)pB;
                    }
                    *(bf16x4v*)(myPA + qc * 72 + nt * 16 + quad * 4) = pkA;
                    *(bf16x4v*)(myPB + qc * 72 + nt * 16 + quad * 4) = pkB;
                }

                // ---- PV for both strips, V from LDS ----
#pragma unroll
                for (int ks = 0; ks < 2; ++ks) {
                    bf16x8 apA = *(const bf16x8*)(myPA + qc * 72 + ks * 32 + quad * 8);
                    bf16x8 apB = *(const bf16x8*)(myPB + qc * 72 + ks * 32 + quad * 8);
#pragma unroll
                    for (int nt = 0; nt < 4; ++nt) {
                        const int d = nt * 16 + qc;
                        bf16x8 vf = *(const bf16x8*)&Vsh[buf][d][((4 * ks + quad) ^ h) * 8];
                        oA[nt] = mfma_bf16(apA, vf, oA[nt]);
                        oB[nt] = mfma_bf16(apB, vf, oB[nt]);
                    }
                }
            }

            // ---- counted wait: tile kb+1 complete, kb+2 stays in flight ----
            if (more2) asm volatile("s_waitcnt vmcnt(4)" ::: "memory");
            else       asm volatile("s_waitcnt vmcnt(0)" ::: "memory");
            __syncthreads();
            const int tswap = b0; b0 = b1; b1 = b2; b2 = tswap;
        }

        // ---- epilogue: write partial (qb, s) ----
        float sumA = (s4A[0] + s4A[1]) + (s4A[2] + s4A[3]);
        float sumB = (s4B[0] + s4B[1]) + (s4B[2] + s4B[3]);
        sumA += __shfl_xor(sumA, 16, 64);
        sumA += __shfl_xor(sumA, 32, 64);
        sumB += __shfl_xor(sumB, 16, 64);
        sumB += __shfl_xor(sumB, 32, 64);

        const int pw = (qb * 16 + bh) * 2 + s;
        float* op = Opart + (size_t)pw * 8192 + (size_t)(wave * 32) * 64;
#pragma unroll
        for (int nt = 0; nt < 4; ++nt)
#pragma unroll
            for (int r = 0; r < 4; ++r) {
                op[(quad * 4 + r) * 64 + nt * 16 + qc]        = oA[nt][r];
                op[1024 + (quad * 4 + r) * 64 + nt * 16 + qc] = oB[nt][r];
            }
        if (quad == 0) {
            float* sp = Spart + (size_t)pw * 128 + wave * 32;
            sp[qc]      = sumA;
            sp[16 + qc] = sumB;
        }
    }
}

// ---------------------------------------------------------------------------
// Combine: 512 units (qb*16+bh) x 128 rows; sum 2 partials, normalize.
// ---------------------------------------------------------------------------
__global__ __launch_bounds__(256) void combine_kernel(
    const float* __restrict__ Opart, const float* __restrict__ Spart,
    bf16* __restrict__ Ob)
{
    const int u  = blockIdx.x;            // 0..511
    const int qb = u >> 4;
    const int bh = u & 15;
    const int c  = threadIdx.x & 63;
    const int g  = threadIdx.x >> 6;
    const int b = bh >> 3, h = bh & 7;

    const float* o0 = Opart + (size_t)(u * 2) * 8192;
    const float* o1 = o0 + 8192;
    const float* s0 = Spart + (size_t)(u * 2) * 128;
    const float* s1 = s0 + 128;

#pragma unroll 4
    for (int rr = 0; rr < 32; ++rr) {
        const int row = g * 32 + rr;
        const float inv = 1.0f / (s0[row] + s1[row]);
        const float v = (o0[row * 64 + c] + o1[row * 64 + c]) * inv;
        const int t = qb * 128 + row;
        Ob[((size_t)b * 4096 + t) * 512 + h * 64 + c] = (bf16)v;
    }
}

extern "C" void kernel_launch(void* const* d_in, const int* in_sizes, int n_in,
                              void* d_out, int out_size, void* d_ws, size_t ws_size,
                              hipStream_t stream)
{
    (void)in_sizes; (void)n_in; (void)out_size; (void)ws_size;
    const void* x  = d_in[0];
    const void* wq = d_in[1];
    const void* wk = d_in[2];
    const void* wv = d_in[3];
    const void* wo = d_in[4];

    char* wsb = (char*)d_ws;
    bf16* xb   = (bf16*)(wsb + 0);          // [8192][512] (aliased by Ob)
    bf16* Ob   = (bf16*)(wsb + 0);
    bf16* wb   = (bf16*)(wsb + 8388608);    // [2048][512]: wq|wk|wv|wo
    bf16* wob  = wb + 3 * 262144;
    bf16* Qb   = (bf16*)(wsb + 10485760);   // [2][8][4096][64]
    bf16* Kb   = (bf16*)(wsb + 18874368);
    bf16* Vb   = (bf16*)(wsb + 27262976);   // [2][8][64][4096]
    int*  flag = (int*) (wsb + 35651584);
    float* Opart = (float*)(wsb + 35651600);   // [1024 pw][128][64] fp32 = 33.5MB
    float* Spart = (float*)(wsb + 69206032);   // [1024 pw][128] fp32 = 512KB

    const dim3 blk(256);

    sniff_dtype<<<1, blk, 0, stream>>>((const uint16_t*)x, flag);
    convert_all<<<2560, blk, 0, stream>>>(x, wq, wk, wv, wo, xb, wb, flag);

    gemm_qkv<<<dim3(12, 64), blk, 0, stream>>>(xb, wb, Qb, Kb, Vb);

    flash_kernel<<<dim3(512), blk, 0, stream>>>(Qb, Kb, Vb, Opart, Spart);
    combine_kernel<<<dim3(512), blk, 0, stream>>>(Opart, Spart, Ob);

    gemm_out_pad<<<dim3(16, 128), blk, 0, stream>>>(Ob, wob, d_out, flag);
}

// Round 7
// 207.652 us; speedup vs baseline: 1.7356x; 1.3369x over previous
//
#include <hip/hip_runtime.h>
#include <hip/hip_bf16.h>
#include <stdint.h>

// ---------------------------------------------------------------------------
// MatryoshkaAttention: B=2, T=4096, D=1024, active_dim=512 -> H=8, hd=64.
// fp32 in/out (sniffed on-device), bf16 MFMA compute.
// R18: two fronts.
// (a) flash VALU diet: R17 counters showed VALUBusy 54% (top pipe). Causes:
//     runtime 3-buf rotation (every LDS access recomputes base+buf*8192),
//     per-step recompute of thread-invariant swizzled LDS addresses, and
//     32 v_add sum + shfl reduce. Fix: 2 buffers with 2x-unrolled loop
//     (buf = literal -> ds offset:imm), hoisted base pointers (XOR variants
//     are +-constant: (quad+4)^h == (quad^h)^4), and row-sum via MFMA
//     ones-trick (sacc = mfma(ap, ones, sacc); D rows = q, all cols equal).
// (b) gemm_out_pad rebuilt on the proven R17 m97 structure (128x128 tile,
//     global_load_lds + XOR swizzle); zero-fill moved to 4 column blocks.
// NO launch_bounds min arg anywhere (R6/R8).
// ---------------------------------------------------------------------------

typedef __bf16 bf16;
typedef bf16  bf16x8 __attribute__((ext_vector_type(8)));
typedef bf16  bf16x4v __attribute__((ext_vector_type(4)));
typedef float f32x4  __attribute__((ext_vector_type(4)));
typedef uint32_t u32x4 __attribute__((ext_vector_type(4)));

#define SCL 0.18033688011112042f   /* 0.125 * log2(e): p = 2^(s*SCL) = e^(s/8) */
#define NEG_BIG (-30000.0f)

static __device__ __forceinline__ f32x4 mfma_bf16(bf16x8 a, bf16x8 b, f32x4 c) {
    return __builtin_amdgcn_mfma_f32_16x16x32_bf16(a, b, c, 0, 0, 0);
}

// async global->LDS, 16B per lane; LDS dest = wave-uniform base + lane*16.
static __device__ __forceinline__ void gl_lds(const bf16* g, bf16* l) {
    __builtin_amdgcn_global_load_lds(
        (const __attribute__((address_space(1))) uint32_t*)(g),
        (__attribute__((address_space(3))) uint32_t*)(l), 16, 0, 0);
}

// ---------------------------------------------------------------------------
__global__ __launch_bounds__(256) void sniff_dtype(
    const uint16_t* __restrict__ x, int* __restrict__ flag)
{
    __shared__ int cnt;
    if (threadIdx.x == 0) cnt = 0;
    __syncthreads();
    int local = 0;
    for (int i = threadIdx.x; i < 2048; i += 256) {
        const int e = (x[i] >> 7) & 0xFF;
        if (e >= 0xC0) ++local;
    }
    if (local) atomicAdd(&cnt, local);
    __syncthreads();
    if (threadIdx.x == 0) *flag = (cnt >= 8) ? 1 : 0;
}

// ---------------------------------------------------------------------------
// One launch converts all five tensors (cols 0..511 of [rows][1024]) into
// packed bf16. Blocks 0..2047: x -> xb. Blocks 2048..2559: weights -> wb.
// ---------------------------------------------------------------------------
__global__ __launch_bounds__(256) void convert_all(
    const void* __restrict__ x,
    const void* __restrict__ wq, const void* __restrict__ wk,
    const void* __restrict__ wv, const void* __restrict__ wo,
    bf16* __restrict__ xb, bf16* __restrict__ wb,
    const int* __restrict__ flag)
{
    const int bid = blockIdx.x;
    const void* src;
    bf16* dst;
    int sub;
    if (bid < 2048) { src = x; dst = xb; sub = bid; }
    else {
        const int w = bid - 2048;
        const int wsel = w >> 7;
        src = (wsel == 0) ? wq : (wsel == 1) ? wk : (wsel == 2) ? wv : wo;
        dst = wb + (size_t)wsel * 262144;
        sub = w & 127;
    }
    const int i = (sub * 256 + threadIdx.x) * 8;
    const int r = i >> 9, c = i & 511;
    bf16x8 v;
    if (*flag) {
        const float* s = (const float*)src + (size_t)r * 1024 + c;
        f32x4 f0 = *(const f32x4*)s;
        f32x4 f1 = *(const f32x4*)(s + 4);
#pragma unroll
        for (int j = 0; j < 4; ++j) { v[j] = (bf16)f0[j]; v[4 + j] = (bf16)f1[j]; }
    } else {
        v = *(const bf16x8*)((const bf16*)src + (size_t)r * 1024 + c);
    }
    *(bf16x8*)(dst + (size_t)r * 512 + c) = v;
}

// ---------------------------------------------------------------------------
// Fused QKV NT GEMM, m97 structure: 128x128 tile, BK=64, LDS double-buffer
// staged via global_load_lds with chunk-XOR swizzle. Grid (12, 64).
// A:[8192][512]; B:[1536][512] = wq|wk|wv contiguous.
// bx 0-3: Q (pre-scaled by SCL), 4-7: K, 8-11: V (transposed direct store).
// ---------------------------------------------------------------------------
__global__ __launch_bounds__(256) void gemm_qkv(
    const bf16* __restrict__ A, const bf16* __restrict__ B,
    bf16* __restrict__ Qb, bf16* __restrict__ Kb, bf16* __restrict__ Vb)
{
    const int bx   = blockIdx.x;            // n-tile 0..11
    const int n0   = bx * 128;
    const int m0   = blockIdx.y * 128;
    const int wave = threadIdx.x >> 6;
    const int lane = threadIdx.x & 63;
    const int col  = lane & 15;
    const int quad = lane >> 4;
    const int wr   = wave >> 1, wc = wave & 1;

    __shared__ __align__(16) bf16 As[2][128][64];
    __shared__ __align__(16) bf16 Bs[2][128][64];

    const int rr = lane >> 3, cc = lane & 7;
    const int cs = (cc ^ rr) * 8;           // pre-swizzled source chunk

    auto stage = [&](int kt, int buf) {
#pragma unroll
        for (int j = 0; j < 4; ++j) {
            const int r0 = wave * 32 + j * 8;      // r0 % 8 == 0 -> row&7 == rr
            gl_lds(A + (size_t)(m0 + r0 + rr) * 512 + kt * 64 + cs, &As[buf][r0][0]);
            gl_lds(B + (size_t)(n0 + r0 + rr) * 512 + kt * 64 + cs, &Bs[buf][r0][0]);
        }
    };

    f32x4 acc[4][4];
#pragma unroll
    for (int m = 0; m < 4; ++m)
#pragma unroll
        for (int n = 0; n < 4; ++n)
#pragma unroll
            for (int r = 0; r < 4; ++r) acc[m][n][r] = 0.0f;

    stage(0, 0);
    asm volatile("s_waitcnt vmcnt(0)" ::: "memory");
    __syncthreads();

    for (int kt = 0; kt < 8; ++kt) {
        const int buf = kt & 1;
        if (kt + 1 < 8) stage(kt + 1, buf ^ 1);

#pragma unroll
        for (int kk = 0; kk < 2; ++kk) {
            bf16x8 af[4], bfr[4];
#pragma unroll
            for (int m = 0; m < 4; ++m) {
                const int row = wr * 64 + m * 16 + col;
                af[m] = *(const bf16x8*)&As[buf][row][(((kk << 2) + quad) ^ (col & 7)) * 8];
            }
#pragma unroll
            for (int n = 0; n < 4; ++n) {
                const int row = wc * 64 + n * 16 + col;
                bfr[n] = *(const bf16x8*)&Bs[buf][row][(((kk << 2) + quad) ^ (col & 7)) * 8];
            }
#pragma unroll
            for (int m = 0; m < 4; ++m)
#pragma unroll
                for (int n = 0; n < 4; ++n)
                    acc[m][n] = mfma_bf16(af[m], bfr[n], acc[m][n]);
        }

        asm volatile("s_waitcnt vmcnt(0)" ::: "memory");
        __syncthreads();
    }

    const int bb = m0 >> 12;

    if (bx < 8) {
        bf16* __restrict__ dst = (bx < 4) ? Qb : Kb;
        const float qs = (bx < 4) ? SCL : 1.0f;     // fold softmax scale into Q
#pragma unroll
        for (int m = 0; m < 4; ++m) {
#pragma unroll
            for (int n = 0; n < 4; ++n) {
#pragma unroll
                for (int r = 0; r < 4; ++r) {
                    const int row = m0 + wr * 64 + m * 16 + quad * 4 + r;
                    const int cnl = (n0 & 511) + wc * 64 + n * 16 + col;
                    const int t = row & 4095;
                    const int h = cnl >> 6, d = cnl & 63;
                    dst[((size_t)(bb * 8 + h) * 4096 + t) * 64 + d] = (bf16)(acc[m][n][r] * qs);
                }
            }
        }
    } else {
        // V: transposed store. acc r-index is contiguous in t -> bf16x4.
        const int h0 = (n0 - 1024) >> 6;            // 0,2,4,6
#pragma unroll
        for (int m = 0; m < 4; ++m) {
#pragma unroll
            for (int n = 0; n < 4; ++n) {
                bf16x4v pk;
#pragma unroll
                for (int r = 0; r < 4; ++r) pk[r] = (bf16)acc[m][n][r];
                const int d  = wc * 64 + n * 16 + col;      // 0..127 in tile
                const int t  = (m0 & 4095) + wr * 64 + m * 16 + quad * 4;
                *(bf16x4v*)(Vb + ((size_t)(bb * 8 + h0 + (d >> 6)) * 64 + (d & 63)) * 4096 + t) = pk;
            }
        }
    }
}

// ---------------------------------------------------------------------------
// Out-projection NT GEMM + fused pad, m97 structure. Grid (8, 64).
// bx 0-3: 128x128 compute tile (C = Ob * wo^T); bx 4-7: zero-fill 128-col
// blocks of the pad region (cols 512..1023).
// ---------------------------------------------------------------------------
__global__ __launch_bounds__(256) void gemm_out_pad(
    const bf16* __restrict__ A, const bf16* __restrict__ B, void* __restrict__ C,
    const int* __restrict__ flag)
{
    const int bx  = blockIdx.x;
    const int m0  = blockIdx.y * 128;
    const int isf = *flag;

    if (bx >= 4) {
        const int c0  = 512 + (bx - 4) * 128;
        const int row = m0 + (threadIdx.x >> 1);
        const int cb  = (threadIdx.x & 1) * 64;
        if (isf) {
            float* p = (float*)C + (size_t)row * 1024 + c0 + cb;
            f32x4 z; z[0] = 0.f; z[1] = 0.f; z[2] = 0.f; z[3] = 0.f;
#pragma unroll
            for (int j = 0; j < 16; ++j) *(f32x4*)(p + j * 4) = z;
        } else {
            bf16* p = (bf16*)C + (size_t)row * 1024 + c0 + cb;
            u32x4 z; z[0] = 0u; z[1] = 0u; z[2] = 0u; z[3] = 0u;
#pragma unroll
            for (int j = 0; j < 8; ++j) *(u32x4*)(p + j * 8) = z;
        }
        return;
    }

    const int n0   = bx * 128;
    const int wave = threadIdx.x >> 6;
    const int lane = threadIdx.x & 63;
    const int col  = lane & 15;
    const int quad = lane >> 4;
    const int wr   = wave >> 1, wc = wave & 1;

    __shared__ __align__(16) bf16 As[2][128][64];
    __shared__ __align__(16) bf16 Bs[2][128][64];

    const int rr = lane >> 3, cc = lane & 7;
    const int cs = (cc ^ rr) * 8;

    auto stage = [&](int kt, int buf) {
#pragma unroll
        for (int j = 0; j < 4; ++j) {
            const int r0 = wave * 32 + j * 8;
            gl_lds(A + (size_t)(m0 + r0 + rr) * 512 + kt * 64 + cs, &As[buf][r0][0]);
            gl_lds(B + (size_t)(n0 + r0 + rr) * 512 + kt * 64 + cs, &Bs[buf][r0][0]);
        }
    };

    f32x4 acc[4][4];
#pragma unroll
    for (int m = 0; m < 4; ++m)
#pragma unroll
        for (int n = 0; n < 4; ++n)
#pragma unroll
            for (int r = 0; r < 4; ++r) acc[m][n][r] = 0.0f;

    stage(0, 0);
    asm volatile("s_waitcnt vmcnt(0)" ::: "memory");
    __syncthreads();

    for (int kt = 0; kt < 8; ++kt) {
        const int buf = kt & 1;
        if (kt + 1 < 8) stage(kt + 1, buf ^ 1);

#pragma unroll
        for (int kk = 0; kk < 2; ++kk) {
            bf16x8 af[4], bfr[4];
#pragma unroll
            for (int m = 0; m < 4; ++m) {
                const int row = wr * 64 + m * 16 + col;
                af[m] = *(const bf16x8*)&As[buf][row][(((kk << 2) + quad) ^ (col & 7)) * 8];
            }
#pragma unroll
            for (int n = 0; n < 4; ++n) {
                const int row = wc * 64 + n * 16 + col;
                bfr[n] = *(const bf16x8*)&Bs[buf][row][(((kk << 2) + quad) ^ (col & 7)) * 8];
            }
#pragma unroll
            for (int m = 0; m < 4; ++m)
#pragma unroll
                for (int n = 0; n < 4; ++n)
                    acc[m][n] = mfma_bf16(af[m], bfr[n], acc[m][n]);
        }

        asm volatile("s_waitcnt vmcnt(0)" ::: "memory");
        __syncthreads();
    }

#pragma unroll
    for (int m = 0; m < 4; ++m) {
#pragma unroll
        for (int n = 0; n < 4; ++n) {
#pragma unroll
            for (int r = 0; r < 4; ++r) {
                const int row = m0 + wr * 64 + m * 16 + quad * 4 + r;
                const int cn  = n0 + wc * 64 + n * 16 + col;
                const float f = acc[m][n][r];
                if (isf) ((float*)C)[(size_t)row * 1024 + cn] = f;
                else     ((bf16*)C)[(size_t)row * 1024 + cn] = (bf16)f;
            }
        }
    }
}

// ---------------------------------------------------------------------------
// Flash causal attention, LDS-shared K/V tiles, 2-buffer + unrolled x2 so
// buf is a compile-time literal (LDS accesses fold to ds offset:imm).
// All LDS base addresses hoisted (thread-invariant); row-sum via MFMA
// ones-trick (no v_add chain, no shfl reduce).
// Block = (bh, qb0, s): q-block qb0 then 31-qb0, K-ranges split so every
// block = 33 tile-steps. Waves own 32 q-rows (2 strips, S^T operand swap).
// ---------------------------------------------------------------------------
__global__ __launch_bounds__(256) void flash_kernel(
    const bf16* __restrict__ Q, const bf16* __restrict__ K,
    const bf16* __restrict__ Vt,
    float* __restrict__ Opart, float* __restrict__ Spart)
{
    const int wave = threadIdx.x >> 6;
    const int lane = threadIdx.x & 63;
    const int qc   = lane & 15;
    const int quad = lane >> 4;

    const int bh  = blockIdx.x & 15;
    const int qb0 = (blockIdx.x >> 4) & 15;
    const int s   = blockIdx.x >> 8;          // 0..1

    const bf16* __restrict__ Qh = Q  + (size_t)bh * (4096 * 64);
    const bf16* __restrict__ Kh = K  + (size_t)bh * (4096 * 64);
    const bf16* __restrict__ Vh = Vt + (size_t)bh * (64 * 4096);

    __shared__ __align__(16) bf16 Ksh[2][64][64];
    __shared__ __align__(16) bf16 Vsh[2][64][64];
    __shared__ __align__(16) bf16 Plds[4][2][16][72];  // per-wave, no barriers

    // ---- hoisted thread-invariant LDS bases ----
    // K/V reads: row nt*16+qc, col swz (or swz^32); buf1 = +4096 elems.
    const int h   = qc & 7;
    const int swz = (quad ^ h) * 8;
    const bf16* kB  = &Ksh[0][qc][swz];
    const bf16* kB2 = &Ksh[0][qc][swz ^ 32];   // ((quad+4)^h)*8 == swz^32
    const bf16* vB  = &Vsh[0][qc][swz];        // ks=0
    const bf16* vB2 = &Vsh[0][qc][swz ^ 32];   // ks=1: ((quad+4ks)^h)*8
    bf16*       pwA = &Plds[wave][0][qc][quad * 4];  // write; +nt*16; +1152 strip B
    const bf16* prA = &Plds[wave][0][qc][quad * 8];  // read;  +ks*32; +1152 strip B

    const int rr = lane >> 3, cc = lane & 7;
    const int cs = (cc ^ rr) * 8;

    bf16x8 vones;
#pragma unroll
    for (int j = 0; j < 8; ++j) vones[j] = (bf16)1.0f;

    auto stage = [&](int kb, int buf) {
#pragma unroll
        for (int j = 0; j < 2; ++j) {
            const int r0 = wave * 16 + j * 8;
            gl_lds(Kh + (size_t)(kb * 64 + r0 + rr) * 64 + cs, &Ksh[buf][r0][0]);
            gl_lds(Vh + (size_t)(r0 + rr) * 4096 + kb * 64 + cs, &Vsh[buf][r0][0]);
        }
    };

    for (int chunk = 0; chunk < 2; ++chunk) {
        const int qb = chunk ? (31 - qb0) : qb0;
        int k0, k1;
        if (chunk == 0) { k0 = s ? (qb0 + 1) : 0;   k1 = s ? (2 * qb0 + 2) : (qb0 + 1); }
        else            { k0 = s ? 0 : (32 - qb0);  k1 = s ? (32 - qb0) : (64 - 2 * qb0); }

        const int qrow   = qb * 128 + wave * 32;    // this wave's 32-row band
        const int ktmaxw = 2 * qb + (wave >> 1);    // wave's diagonal tile

        bf16x8 aqA0 = *(const bf16x8*)(Qh + (size_t)(qrow + qc) * 64 + quad * 8);
        bf16x8 aqA1 = *(const bf16x8*)(Qh + (size_t)(qrow + qc) * 64 + 32 + quad * 8);
        bf16x8 aqB0 = *(const bf16x8*)(Qh + (size_t)(qrow + 16 + qc) * 64 + quad * 8);
        bf16x8 aqB1 = *(const bf16x8*)(Qh + (size_t)(qrow + 16 + qc) * 64 + 32 + quad * 8);

        f32x4 oA[4], oB[4], saccA, saccB;
#pragma unroll
        for (int r = 0; r < 4; ++r) { saccA[r] = 0.f; saccB[r] = 0.f; }
#pragma unroll
        for (int nt = 0; nt < 4; ++nt)
#pragma unroll
            for (int r = 0; r < 4; ++r) { oA[nt][r] = 0.f; oB[nt][r] = 0.f; }

        // step body; buf MUST be a literal at each call site (inlined).
        auto body = [&](const int kb, const int buf) {
            if (kb <= ktmaxw) {
                const bool diag = (kb == ktmaxw);

                // ---- QK^T + exp + pack to P-LDS ----
#pragma unroll
                for (int nt = 0; nt < 4; ++nt) {
                    bf16x8 kf0 = *(const bf16x8*)(kB  + buf * 4096 + nt * 1024);
                    bf16x8 kf1 = *(const bf16x8*)(kB2 + buf * 4096 + nt * 1024);

                    f32x4 sA; sA[0] = 0.f; sA[1] = 0.f; sA[2] = 0.f; sA[3] = 0.f;
                    sA = mfma_bf16(kf0, aqA0, sA);
                    sA = mfma_bf16(kf1, aqA1, sA);
                    f32x4 sB; sB[0] = 0.f; sB[1] = 0.f; sB[2] = 0.f; sB[3] = 0.f;
                    sB = mfma_bf16(kf0, aqB0, sB);
                    sB = mfma_bf16(kf1, aqB1, sB);

                    bf16x4v pkA, pkB;
#pragma unroll
                    for (int r2 = 0; r2 < 4; ++r2) {
                        float vA = sA[r2];          // Q pre-scaled: no mul here
                        float vBv = sB[r2];
                        if (diag) {
                            const int kg = kb * 64 + nt * 16 + quad * 4 + r2;
                            if (kg > qrow + qc)      vA  = NEG_BIG;
                            if (kg > qrow + 16 + qc) vBv = NEG_BIG;
                        }
                        pkA[r2] = (bf16)__builtin_amdgcn_exp2f(vA);
                        pkB[r2] = (bf16)__builtin_amdgcn_exp2f(vBv);
                    }
                    *(bf16x4v*)(pwA + nt * 16)        = pkA;
                    *(bf16x4v*)(pwA + 1152 + nt * 16) = pkB;
                }

                // ---- PV + MFMA-ones row sums ----
#pragma unroll
                for (int ks = 0; ks < 2; ++ks) {
                    bf16x8 apA = *(const bf16x8*)(prA + ks * 32);
                    bf16x8 apB = *(const bf16x8*)(prA + 1152 + ks * 32);
#pragma unroll
                    for (int nt = 0; nt < 4; ++nt) {
                        bf16x8 vf = *(const bf16x8*)((ks ? vB2 : vB) + buf * 4096 + nt * 1024);
                        oA[nt] = mfma_bf16(apA, vf, oA[nt]);
                        oB[nt] = mfma_bf16(apB, vf, oB[nt]);
                    }
                    saccA = mfma_bf16(apA, vones, saccA);
                    saccB = mfma_bf16(apB, vones, saccB);
                }
            }
        };

        stage(k0, 0);
        asm volatile("s_waitcnt vmcnt(0)" ::: "memory");
        __syncthreads();

        int kb = k0;
        while (true) {
            if (kb + 1 < k1) stage(kb + 1, 1);
            body(kb, 0);
            asm volatile("s_waitcnt vmcnt(0)" ::: "memory");
            __syncthreads();
            ++kb; if (kb >= k1) break;

            if (kb + 1 < k1) stage(kb + 1, 0);
            body(kb, 1);
            asm volatile("s_waitcnt vmcnt(0)" ::: "memory");
            __syncthreads();
            ++kb; if (kb >= k1) break;
        }

        // ---- epilogue: write partial (qb, s) ----
        // sacc D-mapping: row q = quad*4 + r (all 16 qc columns identical).
        const int pw = (qb * 16 + bh) * 2 + s;
        float* op = Opart + (size_t)pw * 8192 + (size_t)(wave * 32) * 64;
#pragma unroll
        for (int nt = 0; nt < 4; ++nt)
#pragma unroll
            for (int r = 0; r < 4; ++r) {
                op[(quad * 4 + r) * 64 + nt * 16 + qc]        = oA[nt][r];
                op[1024 + (quad * 4 + r) * 64 + nt * 16 + qc] = oB[nt][r];
            }
        if (qc == 0) {
            float* sp = Spart + (size_t)pw * 128 + wave * 32;
#pragma unroll
            for (int r = 0; r < 4; ++r) {
                sp[quad * 4 + r]      = saccA[r];
                sp[16 + quad * 4 + r] = saccB[r];
            }
        }
    }
}

// ---------------------------------------------------------------------------
// Combine: 512 units (qb*16+bh) x 128 rows; sum 2 partials, normalize.
// ---------------------------------------------------------------------------
__global__ __launch_bounds__(256) void combine_kernel(
    const float* __restrict__ Opart, const float* __restrict__ Spart,
    bf16* __restrict__ Ob)
{
    const int u  = blockIdx.x;            // 0..511
    const int qb = u >> 4;
    const int bh = u & 15;
    const int c  = threadIdx.x & 63;
    const int g  = threadIdx.x >> 6;
    const int b = bh >> 3, h = bh & 7;

    const float* o0 = Opart + (size_t)(u * 2) * 8192;
    const float* o1 = o0 + 8192;
    const float* s0 = Spart + (size_t)(u * 2) * 128;
    const float* s1 = s0 + 128;

#pragma unroll 4
    for (int rr = 0; rr < 32; ++rr) {
        const int row = g * 32 + rr;
        const float inv = 1.0f / (s0[row] + s1[row]);
        const float v = (o0[row * 64 + c] + o1[row * 64 + c]) * inv;
        const int t = qb * 128 + row;
        Ob[((size_t)b * 4096 + t) * 512 + h * 64 + c] = (bf16)v;
    }
}

extern "C" void kernel_launch(void* const* d_in, const int* in_sizes, int n_in,
                              void* d_out, int out_size, void* d_ws, size_t ws_size,
                              hipStream_t stream)
{
    (void)in_sizes; (void)n_in; (void)out_size; (void)ws_size;
    const void* x  = d_in[0];
    const void* wq = d_in[1];
    const void* wk = d_in[2];
    const void* wv = d_in[3];
    const void* wo = d_in[4];

    char* wsb = (char*)d_ws;
    bf16* xb   = (bf16*)(wsb + 0);          // [8192][512] (aliased by Ob)
    bf16* Ob   = (bf16*)(wsb + 0);
    bf16* wb   = (bf16*)(wsb + 8388608);    // [2048][512]: wq|wk|wv|wo
    bf16* wob  = wb + 3 * 262144;
    bf16* Qb   = (bf16*)(wsb + 10485760);   // [2][8][4096][64]
    bf16* Kb   = (bf16*)(wsb + 18874368);
    bf16* Vb   = (bf16*)(wsb + 27262976);   // [2][8][64][4096]
    int*  flag = (int*) (wsb + 35651584);
    float* Opart = (float*)(wsb + 35651600);   // [1024 pw][128][64] fp32 = 33.5MB
    float* Spart = (float*)(wsb + 69206032);   // [1024 pw][128] fp32 = 512KB

    const dim3 blk(256);

    sniff_dtype<<<1, blk, 0, stream>>>((const uint16_t*)x, flag);
    convert_all<<<2560, blk, 0, stream>>>(x, wq, wk, wv, wo, xb, wb, flag);

    gemm_qkv<<<dim3(12, 64), blk, 0, stream>>>(xb, wb, Qb, Kb, Vb);

    flash_kernel<<<dim3(512), blk, 0, stream>>>(Qb, Kb, Vb, Opart, Spart);
    combine_kernel<<<dim3(512), blk, 0, stream>>>(Opart, Spart, Ob);

    gemm_out_pad<<<dim3(8, 64), blk, 0, stream>>>(Ob, wob, d_out, flag);
}

// Round 8
// 205.421 us; speedup vs baseline: 1.7545x; 1.0109x over previous
//
#include <hip/hip_runtime.h>
#include <hip/hip_bf16.h>
#include <stdint.h>

// ---------------------------------------------------------------------------
// MatryoshkaAttention: B=2, T=4096, D=1024, active_dim=512 -> H=8, hd=64.
// fp32 in/out (sniffed on-device), bf16 MFMA compute.
// R19: flash occupancy. R18 counters: occ 18.5% (grid 512 = 2 blocks/CU is
// the limiter; LDS/VGPR allow 3). Split each (bh,qb0) unit's 66-tile budget
// 3 ways (grid 768 = 3 blocks/CU, 22 steps/block, balance by construction).
// Generic contiguous split over concatenated chunk tile-lists; empty chunk
// intersections write zero partials (block-uniform guard). Combine sums
// NSPLIT partials. Host falls back to NSPLIT=2 (exact R18) if ws_size
// < 86.8MB (proven floor is 78.3MB). NO launch_bounds min arg (R6/R8).
// ---------------------------------------------------------------------------

typedef __bf16 bf16;
typedef bf16  bf16x8 __attribute__((ext_vector_type(8)));
typedef bf16  bf16x4v __attribute__((ext_vector_type(4)));
typedef float f32x4  __attribute__((ext_vector_type(4)));
typedef uint32_t u32x4 __attribute__((ext_vector_type(4)));

#define SCL 0.18033688011112042f   /* 0.125 * log2(e): p = 2^(s*SCL) = e^(s/8) */
#define NEG_BIG (-30000.0f)

static __device__ __forceinline__ f32x4 mfma_bf16(bf16x8 a, bf16x8 b, f32x4 c) {
    return __builtin_amdgcn_mfma_f32_16x16x32_bf16(a, b, c, 0, 0, 0);
}

// async global->LDS, 16B per lane; LDS dest = wave-uniform base + lane*16.
static __device__ __forceinline__ void gl_lds(const bf16* g, bf16* l) {
    __builtin_amdgcn_global_load_lds(
        (const __attribute__((address_space(1))) uint32_t*)(g),
        (__attribute__((address_space(3))) uint32_t*)(l), 16, 0, 0);
}

// ---------------------------------------------------------------------------
__global__ __launch_bounds__(256) void sniff_dtype(
    const uint16_t* __restrict__ x, int* __restrict__ flag)
{
    __shared__ int cnt;
    if (threadIdx.x == 0) cnt = 0;
    __syncthreads();
    int local = 0;
    for (int i = threadIdx.x; i < 2048; i += 256) {
        const int e = (x[i] >> 7) & 0xFF;
        if (e >= 0xC0) ++local;
    }
    if (local) atomicAdd(&cnt, local);
    __syncthreads();
    if (threadIdx.x == 0) *flag = (cnt >= 8) ? 1 : 0;
}

// ---------------------------------------------------------------------------
// One launch converts all five tensors (cols 0..511 of [rows][1024]) into
// packed bf16. Blocks 0..2047: x -> xb. Blocks 2048..2559: weights -> wb.
// ---------------------------------------------------------------------------
__global__ __launch_bounds__(256) void convert_all(
    const void* __restrict__ x,
    const void* __restrict__ wq, const void* __restrict__ wk,
    const void* __restrict__ wv, const void* __restrict__ wo,
    bf16* __restrict__ xb, bf16* __restrict__ wb,
    const int* __restrict__ flag)
{
    const int bid = blockIdx.x;
    const void* src;
    bf16* dst;
    int sub;
    if (bid < 2048) { src = x; dst = xb; sub = bid; }
    else {
        const int w = bid - 2048;
        const int wsel = w >> 7;
        src = (wsel == 0) ? wq : (wsel == 1) ? wk : (wsel == 2) ? wv : wo;
        dst = wb + (size_t)wsel * 262144;
        sub = w & 127;
    }
    const int i = (sub * 256 + threadIdx.x) * 8;
    const int r = i >> 9, c = i & 511;
    bf16x8 v;
    if (*flag) {
        const float* s = (const float*)src + (size_t)r * 1024 + c;
        f32x4 f0 = *(const f32x4*)s;
        f32x4 f1 = *(const f32x4*)(s + 4);
#pragma unroll
        for (int j = 0; j < 4; ++j) { v[j] = (bf16)f0[j]; v[4 + j] = (bf16)f1[j]; }
    } else {
        v = *(const bf16x8*)((const bf16*)src + (size_t)r * 1024 + c);
    }
    *(bf16x8*)(dst + (size_t)r * 512 + c) = v;
}

// ---------------------------------------------------------------------------
// Fused QKV NT GEMM, m97 structure: 128x128 tile, BK=64, LDS double-buffer
// staged via global_load_lds with chunk-XOR swizzle. Grid (12, 64).
// bx 0-3: Q (pre-scaled by SCL), 4-7: K, 8-11: V (transposed direct store).
// ---------------------------------------------------------------------------
__global__ __launch_bounds__(256) void gemm_qkv(
    const bf16* __restrict__ A, const bf16* __restrict__ B,
    bf16* __restrict__ Qb, bf16* __restrict__ Kb, bf16* __restrict__ Vb)
{
    const int bx   = blockIdx.x;            // n-tile 0..11
    const int n0   = bx * 128;
    const int m0   = blockIdx.y * 128;
    const int wave = threadIdx.x >> 6;
    const int lane = threadIdx.x & 63;
    const int col  = lane & 15;
    const int quad = lane >> 4;
    const int wr   = wave >> 1, wc = wave & 1;

    __shared__ __align__(16) bf16 As[2][128][64];
    __shared__ __align__(16) bf16 Bs[2][128][64];

    const int rr = lane >> 3, cc = lane & 7;
    const int cs = (cc ^ rr) * 8;           // pre-swizzled source chunk

    auto stage = [&](int kt, int buf) {
#pragma unroll
        for (int j = 0; j < 4; ++j) {
            const int r0 = wave * 32 + j * 8;      // r0 % 8 == 0 -> row&7 == rr
            gl_lds(A + (size_t)(m0 + r0 + rr) * 512 + kt * 64 + cs, &As[buf][r0][0]);
            gl_lds(B + (size_t)(n0 + r0 + rr) * 512 + kt * 64 + cs, &Bs[buf][r0][0]);
        }
    };

    f32x4 acc[4][4];
#pragma unroll
    for (int m = 0; m < 4; ++m)
#pragma unroll
        for (int n = 0; n < 4; ++n)
#pragma unroll
            for (int r = 0; r < 4; ++r) acc[m][n][r] = 0.0f;

    stage(0, 0);
    asm volatile("s_waitcnt vmcnt(0)" ::: "memory");
    __syncthreads();

    for (int kt = 0; kt < 8; ++kt) {
        const int buf = kt & 1;
        if (kt + 1 < 8) stage(kt + 1, buf ^ 1);

#pragma unroll
        for (int kk = 0; kk < 2; ++kk) {
            bf16x8 af[4], bfr[4];
#pragma unroll
            for (int m = 0; m < 4; ++m) {
                const int row = wr * 64 + m * 16 + col;
                af[m] = *(const bf16x8*)&As[buf][row][(((kk << 2) + quad) ^ (col & 7)) * 8];
            }
#pragma unroll
            for (int n = 0; n < 4; ++n) {
                const int row = wc * 64 + n * 16 + col;
                bfr[n] = *(const bf16x8*)&Bs[buf][row][(((kk << 2) + quad) ^ (col & 7)) * 8];
            }
#pragma unroll
            for (int m = 0; m < 4; ++m)
#pragma unroll
                for (int n = 0; n < 4; ++n)
                    acc[m][n] = mfma_bf16(af[m], bfr[n], acc[m][n]);
        }

        asm volatile("s_waitcnt vmcnt(0)" ::: "memory");
        __syncthreads();
    }

    const int bb = m0 >> 12;

    if (bx < 8) {
        bf16* __restrict__ dst = (bx < 4) ? Qb : Kb;
        const float qs = (bx < 4) ? SCL : 1.0f;     // fold softmax scale into Q
#pragma unroll
        for (int m = 0; m < 4; ++m) {
#pragma unroll
            for (int n = 0; n < 4; ++n) {
#pragma unroll
                for (int r = 0; r < 4; ++r) {
                    const int row = m0 + wr * 64 + m * 16 + quad * 4 + r;
                    const int cnl = (n0 & 511) + wc * 64 + n * 16 + col;
                    const int t = row & 4095;
                    const int h = cnl >> 6, d = cnl & 63;
                    dst[((size_t)(bb * 8 + h) * 4096 + t) * 64 + d] = (bf16)(acc[m][n][r] * qs);
                }
            }
        }
    } else {
        // V: transposed store. acc r-index is contiguous in t -> bf16x4.
        const int h0 = (n0 - 1024) >> 6;            // 0,2,4,6
#pragma unroll
        for (int m = 0; m < 4; ++m) {
#pragma unroll
            for (int n = 0; n < 4; ++n) {
                bf16x4v pk;
#pragma unroll
                for (int r = 0; r < 4; ++r) pk[r] = (bf16)acc[m][n][r];
                const int d  = wc * 64 + n * 16 + col;      // 0..127 in tile
                const int t  = (m0 & 4095) + wr * 64 + m * 16 + quad * 4;
                *(bf16x4v*)(Vb + ((size_t)(bb * 8 + h0 + (d >> 6)) * 64 + (d & 63)) * 4096 + t) = pk;
            }
        }
    }
}

// ---------------------------------------------------------------------------
// Out-projection NT GEMM + fused pad, m97 structure. Grid (8, 64).
// bx 0-3: 128x128 compute tile; bx 4-7: zero-fill 128-col pad blocks.
// ---------------------------------------------------------------------------
__global__ __launch_bounds__(256) void gemm_out_pad(
    const bf16* __restrict__ A, const bf16* __restrict__ B, void* __restrict__ C,
    const int* __restrict__ flag)
{
    const int bx  = blockIdx.x;
    const int m0  = blockIdx.y * 128;
    const int isf = *flag;

    if (bx >= 4) {
        const int c0  = 512 + (bx - 4) * 128;
        const int row = m0 + (threadIdx.x >> 1);
        const int cb  = (threadIdx.x & 1) * 64;
        if (isf) {
            float* p = (float*)C + (size_t)row * 1024 + c0 + cb;
            f32x4 z; z[0] = 0.f; z[1] = 0.f; z[2] = 0.f; z[3] = 0.f;
#pragma unroll
            for (int j = 0; j < 16; ++j) *(f32x4*)(p + j * 4) = z;
        } else {
            bf16* p = (bf16*)C + (size_t)row * 1024 + c0 + cb;
            u32x4 z; z[0] = 0u; z[1] = 0u; z[2] = 0u; z[3] = 0u;
#pragma unroll
            for (int j = 0; j < 8; ++j) *(u32x4*)(p + j * 8) = z;
        }
        return;
    }

    const int n0   = bx * 128;
    const int wave = threadIdx.x >> 6;
    const int lane = threadIdx.x & 63;
    const int col  = lane & 15;
    const int quad = lane >> 4;
    const int wr   = wave >> 1, wc = wave & 1;

    __shared__ __align__(16) bf16 As[2][128][64];
    __shared__ __align__(16) bf16 Bs[2][128][64];

    const int rr = lane >> 3, cc = lane & 7;
    const int cs = (cc ^ rr) * 8;

    auto stage = [&](int kt, int buf) {
#pragma unroll
        for (int j = 0; j < 4; ++j) {
            const int r0 = wave * 32 + j * 8;
            gl_lds(A + (size_t)(m0 + r0 + rr) * 512 + kt * 64 + cs, &As[buf][r0][0]);
            gl_lds(B + (size_t)(n0 + r0 + rr) * 512 + kt * 64 + cs, &Bs[buf][r0][0]);
        }
    };

    f32x4 acc[4][4];
#pragma unroll
    for (int m = 0; m < 4; ++m)
#pragma unroll
        for (int n = 0; n < 4; ++n)
#pragma unroll
            for (int r = 0; r < 4; ++r) acc[m][n][r] = 0.0f;

    stage(0, 0);
    asm volatile("s_waitcnt vmcnt(0)" ::: "memory");
    __syncthreads();

    for (int kt = 0; kt < 8; ++kt) {
        const int buf = kt & 1;
        if (kt + 1 < 8) stage(kt + 1, buf ^ 1);

#pragma unroll
        for (int kk = 0; kk < 2; ++kk) {
            bf16x8 af[4], bfr[4];
#pragma unroll
            for (int m = 0; m < 4; ++m) {
                const int row = wr * 64 + m * 16 + col;
                af[m] = *(const bf16x8*)&As[buf][row][(((kk << 2) + quad) ^ (col & 7)) * 8];
            }
#pragma unroll
            for (int n = 0; n < 4; ++n) {
                const int row = wc * 64 + n * 16 + col;
                bfr[n] = *(const bf16x8*)&Bs[buf][row][(((kk << 2) + quad) ^ (col & 7)) * 8];
            }
#pragma unroll
            for (int m = 0; m < 4; ++m)
#pragma unroll
                for (int n = 0; n < 4; ++n)
                    acc[m][n] = mfma_bf16(af[m], bfr[n], acc[m][n]);
        }

        asm volatile("s_waitcnt vmcnt(0)" ::: "memory");
        __syncthreads();
    }

#pragma unroll
    for (int m = 0; m < 4; ++m) {
#pragma unroll
        for (int n = 0; n < 4; ++n) {
#pragma unroll
            for (int r = 0; r < 4; ++r) {
                const int row = m0 + wr * 64 + m * 16 + quad * 4 + r;
                const int cn  = n0 + wc * 64 + n * 16 + col;
                const float f = acc[m][n][r];
                if (isf) ((float*)C)[(size_t)row * 1024 + cn] = f;
                else     ((bf16*)C)[(size_t)row * 1024 + cn] = (bf16)f;
            }
        }
    }
}

// ---------------------------------------------------------------------------
// Flash causal attention, templated NSPLIT-way work split.
// Unit (bh, qb0) = q-blocks {qb0, 31-qb0}, 66 tiles total (all qb0).
// Block s takes the contiguous global-tile range [STEPS*s, STEPS*(s+1)),
// STEPS = 66/NSPLIT; per-chunk intersections may be empty (zero partial).
// Body identical to R18 (2-buf literal, hoisted LDS bases, MFMA-ones sums).
// ---------------------------------------------------------------------------
template<int NSPLIT>
__global__ __launch_bounds__(256) void flash_kernel(
    const bf16* __restrict__ Q, const bf16* __restrict__ K,
    const bf16* __restrict__ Vt,
    float* __restrict__ Opart, float* __restrict__ Spart)
{
    const int wave = threadIdx.x >> 6;
    const int lane = threadIdx.x & 63;
    const int qc   = lane & 15;
    const int quad = lane >> 4;

    const int bh  = blockIdx.x & 15;
    const int qb0 = (blockIdx.x >> 4) & 15;
    const int s   = blockIdx.x >> 8;          // 0..NSPLIT-1

    const int STEPS = 66 / NSPLIT;
    const int g0 = STEPS * s, g1 = g0 + STEPS;

    const bf16* __restrict__ Qh = Q  + (size_t)bh * (4096 * 64);
    const bf16* __restrict__ Kh = K  + (size_t)bh * (4096 * 64);
    const bf16* __restrict__ Vh = Vt + (size_t)bh * (64 * 4096);

    __shared__ __align__(16) bf16 Ksh[2][64][64];
    __shared__ __align__(16) bf16 Vsh[2][64][64];
    __shared__ __align__(16) bf16 Plds[4][2][16][72];  // per-wave, no barriers

    // ---- hoisted thread-invariant LDS bases ----
    const int h   = qc & 7;
    const int swz = (quad ^ h) * 8;
    const bf16* kB  = &Ksh[0][qc][swz];
    const bf16* kB2 = &Ksh[0][qc][swz ^ 32];   // ((quad+4)^h)*8 == swz^32
    const bf16* vB  = &Vsh[0][qc][swz];        // ks=0
    const bf16* vB2 = &Vsh[0][qc][swz ^ 32];   // ks=1
    bf16*       pwA = &Plds[wave][0][qc][quad * 4];  // write; +nt*16; +1152 strip B
    const bf16* prA = &Plds[wave][0][qc][quad * 8];  // read;  +ks*32; +1152 strip B

    const int rr = lane >> 3, cc = lane & 7;
    const int cs = (cc ^ rr) * 8;

    bf16x8 vones;
#pragma unroll
    for (int j = 0; j < 8; ++j) vones[j] = (bf16)1.0f;

    auto stage = [&](int kb, int buf) {
#pragma unroll
        for (int j = 0; j < 2; ++j) {
            const int r0 = wave * 16 + j * 8;
            gl_lds(Kh + (size_t)(kb * 64 + r0 + rr) * 64 + cs, &Ksh[buf][r0][0]);
            gl_lds(Vh + (size_t)(r0 + rr) * 4096 + kb * 64 + cs, &Vsh[buf][r0][0]);
        }
    };

    for (int chunk = 0; chunk < 2; ++chunk) {
        const int qb  = chunk ? (31 - qb0) : qb0;
        const int n0t = 2 * qb0 + 2;          // tiles in chunk0
        const int n1t = 64 - 2 * qb0;         // tiles in chunk1
        int k0, k1;
        if (chunk == 0) {
            k0 = (g0 > 0) ? g0 : 0;
            k1 = (g1 < n0t) ? g1 : n0t;
        } else {
            const int a = g0 - n0t, b2 = g1 - n0t;
            k0 = (a > 0) ? a : 0;
            k1 = (b2 < n1t) ? b2 : n1t;
        }

        const int qrow   = qb * 128 + wave * 32;    // this wave's 32-row band
        const int ktmaxw = 2 * qb + (wave >> 1);    // wave's diagonal tile

        bf16x8 aqA0 = *(const bf16x8*)(Qh + (size_t)(qrow + qc) * 64 + quad * 8);
        bf16x8 aqA1 = *(const bf16x8*)(Qh + (size_t)(qrow + qc) * 64 + 32 + quad * 8);
        bf16x8 aqB0 = *(const bf16x8*)(Qh + (size_t)(qrow + 16 + qc) * 64 + quad * 8);
        bf16x8 aqB1 = *(const bf16x8*)(Qh + (size_t)(qrow + 16 + qc) * 64 + 32 + quad * 8);

        f32x4 oA[4], oB[4], saccA, saccB;
#pragma unroll
        for (int r = 0; r < 4; ++r) { saccA[r] = 0.f; saccB[r] = 0.f; }
#pragma unroll
        for (int nt = 0; nt < 4; ++nt)
#pragma unroll
            for (int r = 0; r < 4; ++r) { oA[nt][r] = 0.f; oB[nt][r] = 0.f; }

        // step body; buf MUST be a literal at each call site (inlined).
        auto body = [&](const int kb, const int buf) {
            if (kb <= ktmaxw) {
                const bool diag = (kb == ktmaxw);

                // ---- QK^T + exp + pack to P-LDS ----
#pragma unroll
                for (int nt = 0; nt < 4; ++nt) {
                    bf16x8 kf0 = *(const bf16x8*)(kB  + buf * 4096 + nt * 1024);
                    bf16x8 kf1 = *(const bf16x8*)(kB2 + buf * 4096 + nt * 1024);

                    f32x4 sA; sA[0] = 0.f; sA[1] = 0.f; sA[2] = 0.f; sA[3] = 0.f;
                    sA = mfma_bf16(kf0, aqA0, sA);
                    sA = mfma_bf16(kf1, aqA1, sA);
                    f32x4 sB; sB[0] = 0.f; sB[1] = 0.f; sB[2] = 0.f; sB[3] = 0.f;
                    sB = mfma_bf16(kf0, aqB0, sB);
                    sB = mfma_bf16(kf1, aqB1, sB);

                    bf16x4v pkA, pkB;
#pragma unroll
                    for (int r2 = 0; r2 < 4; ++r2) {
                        float vA = sA[r2];          // Q pre-scaled: no mul here
                        float vBv = sB[r2];
                        if (diag) {
                            const int kg = kb * 64 + nt * 16 + quad * 4 + r2;
                            if (kg > qrow + qc)      vA  = NEG_BIG;
                            if (kg > qrow + 16 + qc) vBv = NEG_BIG;
                        }
                        pkA[r2] = (bf16)__builtin_amdgcn_exp2f(vA);
                        pkB[r2] = (bf16)__builtin_amdgcn_exp2f(vBv);
                    }
                    *(bf16x4v*)(pwA + nt * 16)        = pkA;
                    *(bf16x4v*)(pwA + 1152 + nt * 16) = pkB;
                }

                // ---- PV + MFMA-ones row sums ----
#pragma unroll
                for (int ks = 0; ks < 2; ++ks) {
                    bf16x8 apA = *(const bf16x8*)(prA + ks * 32);
                    bf16x8 apB = *(const bf16x8*)(prA + 1152 + ks * 32);
#pragma unroll
                    for (int nt = 0; nt < 4; ++nt) {
                        bf16x8 vf = *(const bf16x8*)((ks ? vB2 : vB) + buf * 4096 + nt * 1024);
                        oA[nt] = mfma_bf16(apA, vf, oA[nt]);
                        oB[nt] = mfma_bf16(apB, vf, oB[nt]);
                    }
                    saccA = mfma_bf16(apA, vones, saccA);
                    saccB = mfma_bf16(apB, vones, saccB);
                }
            }
        };

        if (k0 < k1) {                       // block-uniform guard
            stage(k0, 0);
            asm volatile("s_waitcnt vmcnt(0)" ::: "memory");
            __syncthreads();

            int kb = k0;
            while (true) {
                if (kb + 1 < k1) stage(kb + 1, 1);
                body(kb, 0);
                asm volatile("s_waitcnt vmcnt(0)" ::: "memory");
                __syncthreads();
                ++kb; if (kb >= k1) break;

                if (kb + 1 < k1) stage(kb + 1, 0);
                body(kb, 1);
                asm volatile("s_waitcnt vmcnt(0)" ::: "memory");
                __syncthreads();
                ++kb; if (kb >= k1) break;
            }
        }

        // ---- epilogue: write partial (qb, s) (zeros if no tiles) ----
        const int pw = (qb * 16 + bh) * NSPLIT + s;
        float* op = Opart + (size_t)pw * 8192 + (size_t)(wave * 32) * 64;
#pragma unroll
        for (int nt = 0; nt < 4; ++nt)
#pragma unroll
            for (int r = 0; r < 4; ++r) {
                op[(quad * 4 + r) * 64 + nt * 16 + qc]        = oA[nt][r];
                op[1024 + (quad * 4 + r) * 64 + nt * 16 + qc] = oB[nt][r];
            }
        if (qc == 0) {
            float* sp = Spart + (size_t)pw * 128 + wave * 32;
#pragma unroll
            for (int r = 0; r < 4; ++r) {
                sp[quad * 4 + r]      = saccA[r];
                sp[16 + quad * 4 + r] = saccB[r];
            }
        }
    }
}

// ---------------------------------------------------------------------------
// Combine: 512 units (qb*16+bh) x 128 rows; sum NSPLIT partials, normalize.
// ---------------------------------------------------------------------------
template<int NSPLIT>
__global__ __launch_bounds__(256) void combine_kernel(
    const float* __restrict__ Opart, const float* __restrict__ Spart,
    bf16* __restrict__ Ob)
{
    const int u  = blockIdx.x;            // 0..511
    const int qb = u >> 4;
    const int bh = u & 15;
    const int c  = threadIdx.x & 63;
    const int g  = threadIdx.x >> 6;
    const int b = bh >> 3, h = bh & 7;

    const float* o0 = Opart + (size_t)(u * NSPLIT) * 8192;
    const float* s0 = Spart + (size_t)(u * NSPLIT) * 128;

#pragma unroll 4
    for (int rr = 0; rr < 32; ++rr) {
        const int row = g * 32 + rr;
        float ssum = 0.f, osum = 0.f;
#pragma unroll
        for (int j = 0; j < NSPLIT; ++j) {
            ssum += s0[j * 128 + row];
            osum += o0[(size_t)j * 8192 + row * 64 + c];
        }
        const float v = osum / ssum;
        const int t = qb * 128 + row;
        Ob[((size_t)b * 4096 + t) * 512 + h * 64 + c] = (bf16)v;
    }
}

extern "C" void kernel_launch(void* const* d_in, const int* in_sizes, int n_in,
                              void* d_out, int out_size, void* d_ws, size_t ws_size,
                              hipStream_t stream)
{
    (void)in_sizes; (void)n_in; (void)out_size;
    const void* x  = d_in[0];
    const void* wq = d_in[1];
    const void* wk = d_in[2];
    const void* wv = d_in[3];
    const void* wo = d_in[4];

    char* wsb = (char*)d_ws;
    bf16* xb   = (bf16*)(wsb + 0);          // [8192][512] (aliased by Ob)
    bf16* Ob   = (bf16*)(wsb + 0);
    bf16* wb   = (bf16*)(wsb + 8388608);    // [2048][512]: wq|wk|wv|wo
    bf16* wob  = wb + 3 * 262144;
    bf16* Qb   = (bf16*)(wsb + 10485760);   // [2][8][4096][64]
    bf16* Kb   = (bf16*)(wsb + 18874368);
    bf16* Vb   = (bf16*)(wsb + 27262976);   // [2][8][64][4096]
    int*  flag = (int*) (wsb + 35651584);

    // NSPLIT=3 needs 35,651,600 + 512*3*(8192+128)*4 = 86.8MB of ws.
    const size_t need3 = 35651600ull + (size_t)512 * 3 * (8192 + 128) * 4;
    const int nsplit = (ws_size >= need3) ? 3 : 2;

    float* Opart = (float*)(wsb + 35651600);
    float* Spart = (float*)(wsb + 35651600 + (size_t)512 * nsplit * 8192 * 4);

    const dim3 blk(256);

    sniff_dtype<<<1, blk, 0, stream>>>((const uint16_t*)x, flag);
    convert_all<<<2560, blk, 0, stream>>>(x, wq, wk, wv, wo, xb, wb, flag);

    gemm_qkv<<<dim3(12, 64), blk, 0, stream>>>(xb, wb, Qb, Kb, Vb);

    if (nsplit == 3) {
        flash_kernel<3><<<dim3(768), blk, 0, stream>>>(Qb, Kb, Vb, Opart, Spart);
        combine_kernel<3><<<dim3(512), blk, 0, stream>>>(Opart, Spart, Ob);
    } else {
        flash_kernel<2><<<dim3(512), blk, 0, stream>>>(Qb, Kb, Vb, Opart, Spart);
        combine_kernel<2><<<dim3(512), blk, 0, stream>>>(Opart, Spart, Ob);
    }

    gemm_out_pad<<<dim3(8, 64), blk, 0, stream>>>(Ob, wob, d_out, flag);
}